// Round 5
// baseline (111.504 us; speedup 1.0000x reference)
//
#include <hip/hip_runtime.h>
#include <hip/hip_bf16.h>

#define B 32
#define S 8192
#define D 512
#define CODE_START 256
#define CODE_END 257
#define MEM_TOK 258
#define ADDR_KEY 206
#define MEM_STORE 455
#define CHUNK 512
#define NCH (S / CHUNK)  // 16 chunks per row

typedef float f32x4 __attribute__((ext_vector_type(4)));

// ---------------------------------------------------------------------------
// Kernel 1: per-chunk reduce only. carry[b][c] = max CODE_START pos in chunk,
// mince[b][c] = min CODE_END pos in chunk. Grid (NCH, B) x 256 thr.
// ---------------------------------------------------------------------------
__global__ __launch_bounds__(256) void nvm_carry(
    const int* __restrict__ tok, int* __restrict__ carry, int* __restrict__ mince) {
  const int c = blockIdx.x, b = blockIdx.y;
  const int tid = threadIdx.x;
  const int lane = tid & 63, wid = tid >> 6;
  const int p0 = c * CHUNK + 2 * tid;
  int2 tt = reinterpret_cast<const int2*>(tok + b * S + c * CHUNK)[tid];
  int vmax = max(tt.x == CODE_START ? p0 : -1, tt.y == CODE_START ? p0 + 1 : -1);
  int vmin = min(tt.x == CODE_END ? p0 : S, tt.y == CODE_END ? p0 + 1 : S);
  #pragma unroll
  for (int off = 32; off; off >>= 1) {
    vmax = max(vmax, __shfl_down(vmax, off, 64));
    vmin = min(vmin, __shfl_down(vmin, off, 64));
  }
  __shared__ int smax[4], smin[4];
  if (lane == 0) { smax[wid] = vmax; smin[wid] = vmin; }
  __syncthreads();
  if (tid == 0) {
    carry[b * NCH + c] = max(max(smax[0], smax[1]), max(smax[2], smax[3]));
    mince[b * NCH + c] = min(min(smin[0], smin[1]), min(smin[2], smin[3]));
  }
}

__device__ inline int make_pack(int tk, int cs, int p, int f, int mhe) {
  int pk = tk;
  if ((cs >= 0) && (p < f) && (tk < 256)) {
    int sp = p - cs - 1;
    if (sp < 0) sp = 0;
    int q = sp / 5;
    int r = sp - q * 5;
    int addr = q * 8 + r;
    pk |= (1 << 9) | ((addr & 15) << 12) | (((addr >> 4) & 15) << 16) |
          (((addr >> 8) & 15) << 20);
  }
  if (tk == MEM_TOK && p < mhe) pk |= (1 << 10);
  return pk;
}

// ---------------------------------------------------------------------------
// Kernel 2: one block per chunk. Phase A: in-register chunk scan + carry
// prefix + per-token metadata pack into LDS. Phase B: stream 1 MiB out.
// ---------------------------------------------------------------------------
__global__ __launch_bounds__(256) void nvm_main(
    const int* __restrict__ tok, const float* __restrict__ table,
    const int* __restrict__ carry, const int* __restrict__ mince,
    const int* __restrict__ mhe_p, float* __restrict__ out) {
  const int c = blockIdx.x, b = blockIdx.y;
  const int tid = threadIdx.x;
  const int lane = tid & 63, wid = tid >> 6;
  const int base = c * CHUNK;

  __shared__ int pack_sh[CHUNK];
  __shared__ int wt[4];

  // ---- phase A: local scan + metadata pack ----
  int2 tt = reinterpret_cast<const int2*>(tok + b * S + base)[tid];
  const int p0 = base + 2 * tid;
  const int v0 = (tt.x == CODE_START) ? p0 : -1;
  const int v1 = (tt.y == CODE_START) ? p0 + 1 : -1;
  const int i1 = max(v0, v1);
  int incl = i1;
  #pragma unroll
  for (int off = 1; off < 64; off <<= 1) {
    int u = __shfl_up(incl, off, 64);
    if (lane >= off) incl = max(incl, u);
  }
  int ex = __shfl_up(incl, 1, 64);
  if (lane == 0) ex = -1;
  if (lane == 63) wt[wid] = incl;
  __syncthreads();
  int pre = -1;
  for (int w = 0; w < wid; ++w) pre = max(pre, wt[w]);
  for (int c2 = 0; c2 < c; ++c2) pre = max(pre, carry[b * NCH + c2]);
  ex = max(ex, pre);
  const int cs0 = max(ex, v0);
  const int cs1 = max(ex, i1);

  int f = S;
  #pragma unroll
  for (int c2 = 0; c2 < NCH; ++c2) f = min(f, mince[b * NCH + c2]);
  const int mhe = mhe_p[0];

  pack_sh[2 * tid] = make_pack(tt.x, cs0, p0, f, mhe);
  pack_sh[2 * tid + 1] = make_pack(tt.y, cs1, p0 + 1, f, mhe);
  __syncthreads();

  // ---- phase B: stream ----
  const int ln = tid & 127;      // float4 index within token
  const int half = tid >> 7;     // which token of the pair per iteration
  const int c0 = ln * 4;
  float* outb = out + (size_t)(b * S + base) * D;

  #pragma unroll 4
  for (int j = 0; j < CHUNK / 2; ++j) {
    const int i = 2 * j + half;
    const int p = pack_sh[i];
    const int tk = p & 511;
    f32x4 v = *reinterpret_cast<const f32x4*>(table + tk * D + c0);
    if (p & (1 << 9)) {
      const int ca = ADDR_KEY + ((p >> 12) & 15);
      const int cb = ADDR_KEY + 16 + ((p >> 16) & 15);
      const int cc = ADDR_KEY + 32 + ((p >> 20) & 15);
      #pragma unroll
      for (int u = 0; u < 4; ++u) {
        const int ch = c0 + u;
        if (ch == ca || ch == cb || ch == cc) v[u] = 1.0f;
      }
    }
    if ((p & (1 << 10)) && c0 == (MEM_STORE & ~3)) v[MEM_STORE & 3] = 1.0f;
    __builtin_nontemporal_store(v, reinterpret_cast<f32x4*>(outb + (size_t)i * D + c0));
  }
}

extern "C" void kernel_launch(void* const* d_in, const int* in_sizes, int n_in,
                              void* d_out, int out_size, void* d_ws, size_t ws_size,
                              hipStream_t stream) {
  const int* tok = (const int*)d_in[0];
  const float* table = (const float*)d_in[1];
  const int* mhe = (const int*)d_in[2];
  float* out = (float*)d_out;

  int* carry = (int*)d_ws;            // B*NCH ints
  int* mince = carry + B * NCH;       // B*NCH ints

  nvm_carry<<<dim3(NCH, B), 256, 0, stream>>>(tok, carry, mince);
  nvm_main<<<dim3(NCH, B), 256, 0, stream>>>(tok, table, carry, mince, mhe, out);
}

// Round 6
// 106.434 us; speedup vs baseline: 1.0476x; 1.0476x over previous
//
#include <hip/hip_runtime.h>
#include <hip/hip_bf16.h>

#define B 32
#define S 8192
#define D 512
#define CODE_START 256
#define CODE_END 257
#define MEM_TOK 258
#define ADDR_KEY 206
#define MEM_STORE 455
#define SUB 128
#define NSUB (S / SUB)  // 64 sub-chunks per row

typedef float f32x4 __attribute__((ext_vector_type(4)));
typedef int i32x4 __attribute__((ext_vector_type(4)));

__device__ inline int make_pack(int tk, int cs, int p, int f, int mhe) {
  int pk = tk;
  if ((cs >= 0) && (p < f) && (tk < 256)) {
    int sp = p - cs - 1;
    if (sp < 0) sp = 0;
    int q = sp / 5;
    int r = sp - q * 5;
    int addr = q * 8 + r;
    pk |= (1 << 9) | ((addr & 15) << 12) | (((addr >> 4) & 15) << 16) |
          (((addr >> 8) & 15) << 20);
  }
  if (tk == MEM_TOK && p < mhe) pk |= (1 << 10);
  return pk;
}

// ---------------------------------------------------------------------------
// Single fused kernel. Grid (NSUB, B) = 2048 blocks, 256 threads.
// Phase A: full-row read (L2-hot) -> pre_carry + fce; 2-wave local scan;
//          pack per-token metadata into LDS.
// Phase B: gather + patch + nontemporal stream of 128 tokens (256 KB).
// ---------------------------------------------------------------------------
__global__ __launch_bounds__(256) void nvm_fused(
    const int* __restrict__ tok, const float* __restrict__ table,
    const int* __restrict__ mhe_p, float* __restrict__ out) {
  const int c = blockIdx.x;
  const int b = blockIdx.y;
  const int tid = threadIdx.x;
  const int lane = tid & 63, wid = tid >> 6;
  const int base = c * SUB;
  const int* row = tok + b * S;

  __shared__ int red_max[4], red_min[4], wt[2];
  __shared__ int pack_sh[SUB];

  // ---- full-row reduce: pre-carry (max CS pos < base), fce (min CE pos) ----
  int vmax = -1, vmin = S;
  #pragma unroll
  for (int k = 0; k < 8; ++k) {
    const i32x4 q = reinterpret_cast<const i32x4*>(row)[tid + 256 * k];
    const int p = 4 * (tid + 256 * k);
    #pragma unroll
    for (int e = 0; e < 4; ++e) {
      const int t = q[e], pp = p + e;
      if (t == CODE_START && pp < base) vmax = max(vmax, pp);
      if (t == CODE_END) vmin = min(vmin, pp);
    }
  }
  #pragma unroll
  for (int off = 32; off; off >>= 1) {
    vmax = max(vmax, __shfl_down(vmax, off, 64));
    vmin = min(vmin, __shfl_down(vmin, off, 64));
  }
  if (lane == 0) { red_max[wid] = vmax; red_min[wid] = vmin; }

  // ---- local inclusive scan over [base, base+SUB), threads 0..127 ----
  int myTok = 0, v = -1;
  if (tid < SUB) {
    myTok = row[base + tid];
    v = (myTok == CODE_START) ? (base + tid) : -1;
  }
  int incl = v;
  #pragma unroll
  for (int off = 1; off < 64; off <<= 1) {
    const int u = __shfl_up(incl, off, 64);
    if (lane >= off) incl = max(incl, u);
  }
  if (tid < SUB && lane == 63) wt[wid] = incl;  // wid = 0 or 1
  __syncthreads();

  const int pre = max(max(red_max[0], red_max[1]), max(red_max[2], red_max[3]));
  const int fce = min(min(red_min[0], red_min[1]), min(red_min[2], red_min[3]));
  const int mhe = mhe_p[0];

  if (tid < SUB) {
    const int ex = (wid == 1) ? wt[0] : -1;
    const int cs = max(max(incl, ex), pre);
    pack_sh[tid] = make_pack(myTok, cs, base + tid, fce, mhe);
  }
  __syncthreads();

  // ---- phase B: stream 128 tokens ----
  const int ln = tid & 127, half = tid >> 7;
  const int c0 = ln * 4;
  float* outb = out + (size_t)(b * S + base) * D;

  #pragma unroll 4
  for (int j = 0; j < SUB / 2; ++j) {
    const int i = 2 * j + half;
    const int p = pack_sh[i];
    const int tk = p & 511;
    f32x4 v4 = *reinterpret_cast<const f32x4*>(table + tk * D + c0);
    if (p & (1 << 9)) {
      const int ca = ADDR_KEY + ((p >> 12) & 15);
      const int cb = ADDR_KEY + 16 + ((p >> 16) & 15);
      const int cc = ADDR_KEY + 32 + ((p >> 20) & 15);
      #pragma unroll
      for (int u = 0; u < 4; ++u) {
        const int ch = c0 + u;
        if (ch == ca || ch == cb || ch == cc) v4[u] = 1.0f;
      }
    }
    if ((p & (1 << 10)) && c0 == (MEM_STORE & ~3)) v4[MEM_STORE & 3] = 1.0f;
    __builtin_nontemporal_store(v4, reinterpret_cast<f32x4*>(outb + (size_t)i * D + c0));
  }
}

extern "C" void kernel_launch(void* const* d_in, const int* in_sizes, int n_in,
                              void* d_out, int out_size, void* d_ws, size_t ws_size,
                              hipStream_t stream) {
  const int* tok = (const int*)d_in[0];
  const float* table = (const float*)d_in[1];
  const int* mhe = (const int*)d_in[2];
  float* out = (float*)d_out;

  nvm_fused<<<dim3(NSUB, B), 256, 0, stream>>>(tok, table, mhe, out);
}